// Round 21
// baseline (582.746 us; speedup 1.0000x reference)
//
#include <hip/hip_runtime.h>
#include <math.h>

#define N_DST   32768
#define N_EDGE  524288
#define LN_EPS  1e-5f

// ---------- prep: zq, Wv transpose, wout transpose ----------
__global__ void k_prep(const float* __restrict__ wkv_w, const float* __restrict__ wq_w,
                       const float* __restrict__ wq_b, const float* __restrict__ time_b,
                       const float* __restrict__ wout_w,
                       float* __restrict__ zq, float* __restrict__ Wvt,
                       float* __restrict__ wout_t) {
    int idx = blockIdx.x * 256 + threadIdx.x;
    if (idx < 100) {
        float acc = wq_b[idx];
        for (int j = 0; j < 100; ++j)
            acc += cosf(time_b[j]) * wq_w[idx * 200 + 100 + j];
        zq[idx] = acc;
    } else if (idx < 30100) {
        int r = idx - 100, cc = r / 100, o = r % 100;
        Wvt[r] = wkv_w[(size_t)(100 + o) * 300 + cc];
    } else if (idx < 50100) {
        int r = idx - 30100;
        wout_t[r] = wout_w[(size_t)(r % 100) * 200 + r / 100];
    }
}

// ---------- A2/C2: fold Q-projection into QW map (j<600: X dims; j=600+h: K-bias dot) ----------
__global__ void k_precomp(const float* __restrict__ wq_w, const float* __restrict__ wkv_w,
                          const float* __restrict__ wkv_b, const float* __restrict__ zq,
                          float* __restrict__ A2, float* __restrict__ C2) {
    int idx = blockIdx.x * 256 + threadIdx.x;
    if (idx < 60200) {
        int i = idx / 602, j = idx % 602;
        float acc = 0.f;
        if (j < 600) {
            int h = j / 300, cc = j % 300;
            const float* __restrict__ wq = wq_w + (size_t)(h * 50) * 200 + i;
            const float* __restrict__ wk = wkv_w + (size_t)(h * 50) * 300 + cc;
            #pragma unroll 10
            for (int d = 0; d < 50; ++d)
                acc = fmaf(wq[(size_t)d * 200], wk[(size_t)d * 300], acc);
        } else {
            int h = j - 600;
            const float* __restrict__ wq = wq_w + (size_t)(h * 50) * 200 + i;
            for (int d = 0; d < 50; ++d)
                acc = fmaf(wq[(size_t)d * 200], wkv_b[h * 50 + d], acc);
        }
        A2[idx] = acc;
    } else if (idx < 60802) {
        int j = idx - 60200;
        float acc = 0.f;
        if (j < 600) {
            int h = j / 300, cc = j % 300;
            for (int d = 0; d < 50; ++d)
                acc = fmaf(zq[h * 50 + d], wkv_w[(size_t)(h * 50 + d) * 300 + cc], acc);
        } else {
            int h = j - 600;
            for (int d = 0; d < 50; ++d)
                acc = fmaf(zq[h * 50 + d], wkv_b[h * 50 + d], acc);
        }
        C2[j] = acc;
    }
}

// ---------- CSR offsets via binary search over sorted edge_dst ----------
__global__ void k_offsets(const int* __restrict__ dst, int* __restrict__ off) {
    int n = blockIdx.x * 256 + threadIdx.x;
    if (n > N_DST) return;
    int lo = 0, hi = N_EDGE;
    while (lo < hi) {
        int mid = (lo + hi) >> 1;
        if (dst[mid] < n) lo = mid + 1; else hi = mid;
    }
    off[n] = lo;
}

// ---------- QW = dst_h @ A2 + C2 : transposed LDS tile, b128 broadcast reads ----------
__global__ __launch_bounds__(256) void k_qw(const float* __restrict__ dst_h,
                                            const float* __restrict__ A2,
                                            const float* __restrict__ C2,
                                            float* __restrict__ QW) {
    __shared__ float DsT[100][36];           // pad 36: rows 144 B -> float4-aligned
    int n0 = blockIdx.x * 32, t = threadIdx.x;
    for (int idx = t; idx < 3200; idx += 256) {
        int n = idx / 100, k = idx % 100;
        DsT[k][n] = dst_h[(size_t)(n0 + n) * 100 + k];
    }
    __syncthreads();
    for (int pass = 0; pass < 3; ++pass) {
        int c = pass * 256 + t;
        if (c >= 602) break;
        float cb = C2[c];
        float acc[32];
        #pragma unroll
        for (int n = 0; n < 32; ++n) acc[n] = cb;
        for (int k = 0; k < 100; ++k) {
            float a = A2[(size_t)k * 602 + c];
            #pragma unroll
            for (int q = 0; q < 8; ++q) {
                float4 d = *(const float4*)&DsT[k][q * 4];
                acc[q * 4 + 0] = fmaf(d.x, a, acc[q * 4 + 0]);
                acc[q * 4 + 1] = fmaf(d.y, a, acc[q * 4 + 1]);
                acc[q * 4 + 2] = fmaf(d.z, a, acc[q * 4 + 2]);
                acc[q * 4 + 3] = fmaf(d.w, a, acc[q * 4 + 3]);
            }
        }
        #pragma unroll
        for (int n = 0; n < 32; ++n) QW[(size_t)(n0 + n) * 608 + c] = acc[n];
    }
}

// ---------- k_node: flash streaming + IN-BLOCK V-contraction (Xagg never hits HBM) ----------
// Phase 1 (per wave = 1 node): online-softmax Xagg -> 9.6 KB LDS.
// Phase 2 (block-cooperative): agg[4n][100] = Xagg . Wvt + b_v (Wvt streamed once/block).
__global__ __launch_bounds__(256) void k_node(
        const float* __restrict__ src_h, const float* __restrict__ efeat,
        const float* __restrict__ td,
        const float* __restrict__ time_w, const float* __restrict__ time_b,
        const float* __restrict__ QW, const int* __restrict__ off,
        const float* __restrict__ Wvt, const float* __restrict__ wkv_b,
        float* __restrict__ agg) {
    const int t = threadIdx.x, lane = t & 63, w = t >> 6;
    const int n = blockIdx.x * 4 + w;
    __shared__ float Xs[4][600];
    __shared__ int hasf[4];
    const int r0 = off[n], cnt = off[n + 1] - r0;

    if (cnt <= 0) {
        #pragma unroll
        for (int s = 0; s < 5; ++s) {
            int cc = s * 64 + lane;
            if (cc < 300) { Xs[w][cc] = 0.f; Xs[w][300 + cc] = 0.f; }
        }
        if (lane == 0) hasf[w] = 0;
    } else {
        float qw0[5], qw1[5];
        #pragma unroll
        for (int s = 0; s < 5; ++s) {
            int cc = s * 64 + lane;
            qw0[s] = (cc < 300) ? QW[(size_t)n * 608 + cc]       : 0.f;
            qw1[s] = (cc < 300) ? QW[(size_t)n * 608 + 300 + cc] : 0.f;
        }
        const float B0 = QW[(size_t)n * 608 + 600];
        const float B1 = QW[(size_t)n * 608 + 601];
        float tw3 = 0.f, tb3 = 0.f, tw4 = 0.f, tb4 = 0.f;
        if (lane >= 8) { tw3 = time_w[lane - 8]; tb3 = time_b[lane - 8]; }
        if (lane < 44) { tw4 = time_w[56 + lane]; tb4 = time_b[56 + lane]; }

        auto LOADX = [&](float* x, int r) {
            const float* __restrict__ sr = src_h + (size_t)r * 100;
            const float* __restrict__ er = efeat + (size_t)r * 100;
            const float tdv = td[r];
            x[0] = sr[lane];
            x[1] = (lane < 36) ? sr[64 + lane] : er[lane - 36];
            x[2] = er[28 + lane];
            x[3] = (lane < 8) ? er[92 + lane] : __cosf(fmaf(tdv, tw3, tb3));
            x[4] = (lane < 44) ? __cosf(fmaf(tdv, tw4, tb4)) : 0.f;
        };

        float m0 = -1e30f, m1 = -1e30f, sum0 = 0.f, sum1 = 0.f;
        float a0[5] = {0.f, 0.f, 0.f, 0.f, 0.f}, a1[5] = {0.f, 0.f, 0.f, 0.f, 0.f};

        auto UPDATE = [&](float l0, float l1, const float* x) {
            l0 = l0 > 0.f ? l0 : 0.2f * l0;
            l1 = l1 > 0.f ? l1 : 0.2f * l1;
            if (l0 <= m0 && l1 <= m1) {      // wave-uniform fast path (r == 1 exactly)
                float w0 = __expf(l0 - m0), w1 = __expf(l1 - m1);
                sum0 += w0; sum1 += w1;
                #pragma unroll
                for (int s = 0; s < 5; ++s) {
                    a0[s] = fmaf(w0, x[s], a0[s]);
                    a1[s] = fmaf(w1, x[s], a1[s]);
                }
            } else {
                float m0n = fmaxf(m0, l0), m1n = fmaxf(m1, l1);
                float r0f = __expf(m0 - m0n), r1f = __expf(m1 - m1n);
                float w0 = __expf(l0 - m0n),  w1 = __expf(l1 - m1n);
                sum0 = fmaf(sum0, r0f, w0);
                sum1 = fmaf(sum1, r1f, w1);
                #pragma unroll
                for (int s = 0; s < 5; ++s) {
                    a0[s] = fmaf(a0[s], r0f, w0 * x[s]);
                    a1[s] = fmaf(a1[s], r1f, w1 * x[s]);
                }
                m0 = m0n; m1 = m1n;
            }
        };

        float xA[5], xB[5], xC[5], xD[5];
        int i = 0;
        if (cnt >= 2) {
            LOADX(xA, r0); LOADX(xB, r0 + 1);
            for (; i + 2 <= cnt; i += 2) {
                float pA0 = 0.f, pA1 = 0.f, pB0 = 0.f, pB1 = 0.f;
                #pragma unroll
                for (int s = 0; s < 5; ++s) {
                    pA0 = fmaf(xA[s], qw0[s], pA0); pA1 = fmaf(xA[s], qw1[s], pA1);
                    pB0 = fmaf(xB[s], qw0[s], pB0); pB1 = fmaf(xB[s], qw1[s], pB1);
                }
                #pragma unroll
                for (int sh = 1; sh < 64; sh <<= 1) {
                    pA0 += __shfl_xor(pA0, sh); pA1 += __shfl_xor(pA1, sh);
                    pB0 += __shfl_xor(pB0, sh); pB1 += __shfl_xor(pB1, sh);
                }
                if (i + 2 < cnt) LOADX(xC, r0 + i + 2);
                if (i + 3 < cnt) LOADX(xD, r0 + i + 3);
                UPDATE(pA0 + B0, pA1 + B1, xA);
                UPDATE(pB0 + B0, pB1 + B1, xB);
                #pragma unroll
                for (int s = 0; s < 5; ++s) { xA[s] = xC[s]; xB[s] = xD[s]; }
            }
        } else {
            LOADX(xA, r0);
        }
        if (i < cnt) {
            float p0 = 0.f, p1 = 0.f;
            #pragma unroll
            for (int s = 0; s < 5; ++s) {
                p0 = fmaf(xA[s], qw0[s], p0);
                p1 = fmaf(xA[s], qw1[s], p1);
            }
            #pragma unroll
            for (int sh = 1; sh < 64; sh <<= 1) {
                p0 += __shfl_xor(p0, sh); p1 += __shfl_xor(p1, sh);
            }
            UPDATE(p0 + B0, p1 + B1, xA);
        }
        const float inv0 = 1.f / sum0, inv1 = 1.f / sum1;
        #pragma unroll
        for (int s = 0; s < 5; ++s) {
            int cc = s * 64 + lane;
            if (cc < 300) {
                Xs[w][cc]       = a0[s] * inv0;
                Xs[w][300 + cc] = a1[s] * inv1;
            }
        }
        if (lane == 0) hasf[w] = 1;
    }
    __syncthreads();

    // ---- phase 2: agg[n][o] = Xs[n][h(o)] . Wvt[:,o] + b_v[o]*has. 400 items / 256 thr ----
    const int bn0 = blockIdx.x * 4;
    const int o0 = t % 100, n0i = t / 100;
    const bool ok1 = (t < 144);
    const int it1 = t + 256;
    const int o1 = ok1 ? (it1 % 100) : o0;
    const int n1i = ok1 ? (it1 / 100) : 0;
    const float* __restrict__ x0 = &Xs[n0i][(o0 / 50) * 300];
    const float* __restrict__ x1 = &Xs[n1i][(o1 / 50) * 300];
    float A0 = hasf[n0i] ? wkv_b[100 + o0] : 0.f;
    float A1 = (ok1 && hasf[n1i]) ? wkv_b[100 + o1] : 0.f;
    #pragma unroll 4
    for (int cc = 0; cc < 300; ++cc) {
        float w0 = Wvt[cc * 100 + o0];
        float w1 = Wvt[cc * 100 + o1];
        A0 = fmaf(x0[cc], w0, A0);
        A1 = fmaf(x1[cc], w1, A1);
    }
    agg[(size_t)(bn0 + n0i) * 100 + o0] = A0;
    if (ok1) agg[(size_t)(bn0 + n1i) * 100 + o1] = A1;
}

// ---------- out proj + relu + layernorm: 8 nodes/block, coalesced wout_t (round-18 proven) ----------
__global__ __launch_bounds__(128) void k_out(const float* __restrict__ agg,
                                             const float* __restrict__ dst_h,
                                             const float* __restrict__ wout_t,
                                             const float* __restrict__ wout_b,
                                             const float* __restrict__ ln_g,
                                             const float* __restrict__ ln_b,
                                             float* __restrict__ out) {
    __shared__ float Fs[8][200];
    __shared__ float red[8][128];
    const int n0 = blockIdx.x * 8, t = threadIdx.x;
    for (int idx = t; idx < 1600; idx += 128) {
        int n = idx / 200, i = idx % 200;
        Fs[n][i] = (i < 100) ? agg[(size_t)(n0 + n) * 100 + i]
                             : dst_h[(size_t)(n0 + n) * 100 + (i - 100)];
    }
    __syncthreads();
    float v[8] = {0.f, 0.f, 0.f, 0.f, 0.f, 0.f, 0.f, 0.f};
    if (t < 100) {
        float b = wout_b[t];
        #pragma unroll
        for (int n = 0; n < 8; ++n) v[n] = b;
        for (int i = 0; i < 200; ++i) {
            float w = wout_t[i * 100 + t];
            #pragma unroll
            for (int n = 0; n < 8; ++n) v[n] = fmaf(Fs[n][i], w, v[n]);
        }
        #pragma unroll
        for (int n = 0; n < 8; ++n) v[n] = fmaxf(v[n], 0.f);
    }
    #pragma unroll
    for (int n = 0; n < 8; ++n) red[n][t] = (t < 100) ? v[n] : 0.f;
    __syncthreads();
    for (int s = 64; s > 0; s >>= 1) {
        if (t < s) {
            #pragma unroll
            for (int n = 0; n < 8; ++n) red[n][t] += red[n][t + s];
        }
        __syncthreads();
    }
    float mu[8];
    #pragma unroll
    for (int n = 0; n < 8; ++n) mu[n] = red[n][0] * 0.01f;
    __syncthreads();
    #pragma unroll
    for (int n = 0; n < 8; ++n) {
        float dv = (t < 100) ? (v[n] - mu[n]) : 0.f;
        red[n][t] = dv * dv;
    }
    __syncthreads();
    for (int s = 64; s > 0; s >>= 1) {
        if (t < s) {
            #pragma unroll
            for (int n = 0; n < 8; ++n) red[n][t] += red[n][t + s];
        }
        __syncthreads();
    }
    if (t < 100) {
        #pragma unroll
        for (int n = 0; n < 8; ++n) {
            float var = red[n][0] * 0.01f;
            out[(size_t)(n0 + n) * 100 + t] =
                (v[n] - mu[n]) * rsqrtf(var + LN_EPS) * ln_g[t] + ln_b[t];
        }
    }
}

extern "C" void kernel_launch(void* const* d_in, const int* in_sizes, int n_in,
                              void* d_out, int out_size, void* d_ws, size_t ws_size,
                              hipStream_t stream) {
    const float* dst_h   = (const float*)d_in[0];
    const float* src_h   = (const float*)d_in[1];
    const float* efeat   = (const float*)d_in[2];
    const float* td      = (const float*)d_in[3];
    const int*   edst    = (const int*)  d_in[4];
    const float* time_w  = (const float*)d_in[5];
    const float* time_b  = (const float*)d_in[6];
    const float* wq_w    = (const float*)d_in[7];
    const float* wq_b    = (const float*)d_in[8];
    const float* wkv_w   = (const float*)d_in[9];
    const float* wkv_b   = (const float*)d_in[10];
    const float* wout_w  = (const float*)d_in[11];
    const float* wout_b  = (const float*)d_in[12];
    const float* ln_g    = (const float*)d_in[13];
    const float* ln_b    = (const float*)d_in[14];
    float* out = (float*)d_out;

    char* ws = (char*)d_ws;
    size_t off = 0;
    auto carve = [&](size_t bytes) { char* p = ws + off; off = (off + bytes + 255) & ~(size_t)255; return p; };
    float* QW    = (float*)carve((size_t)N_DST * 608 * 4);
    float* agg   = (float*)carve((size_t)N_DST * 100 * 4);
    float* A2    = (float*)carve(60200 * 4);
    float* C2    = (float*)carve(602 * 4);
    float* Wvt   = (float*)carve(30000 * 4);
    float* woutT = (float*)carve(20000 * 4);
    float* zq    = (float*)carve(100 * 4);
    int*   offs  = (int*)carve((size_t)(N_DST + 1) * 4);

    k_prep<<<(50100 + 255) / 256, 256, 0, stream>>>(wkv_w, wq_w, wq_b, time_b, wout_w,
                                                    zq, Wvt, woutT);
    k_precomp<<<(60802 + 255) / 256, 256, 0, stream>>>(wq_w, wkv_w, wkv_b, zq, A2, C2);
    k_offsets<<<(N_DST + 1 + 255) / 256, 256, 0, stream>>>(edst, offs);
    k_qw<<<N_DST / 32, 256, 0, stream>>>(dst_h, A2, C2, QW);
    k_node<<<N_DST / 4, 256, 0, stream>>>(src_h, efeat, td, time_w, time_b,
                                          QW, offs, Wvt, wkv_b, agg);
    k_out<<<N_DST / 8, 128, 0, stream>>>(agg, dst_h, woutT, wout_b, ln_g, ln_b, out);
}

// Round 22
// 327.223 us; speedup vs baseline: 1.7809x; 1.7809x over previous
//
#include <hip/hip_runtime.h>
#include <math.h>

#define N_DST   32768
#define N_EDGE  524288
#define LN_EPS  1e-5f

typedef __attribute__((ext_vector_type(8))) short short8b;   // 8 bf16 (4 VGPR)
typedef __attribute__((ext_vector_type(4))) float f32x4;

static __device__ __forceinline__ unsigned short f2bf(float f) {
    unsigned u = __float_as_uint(f);
    u += 0x7fff + ((u >> 16) & 1);          // round-to-nearest-even
    return (unsigned short)(u >> 16);
}

// ---------- prep: zq, wout^T, Bv pack (block-diag V weights -> MFMA B-frag order) ----------
// Bv[kc<21][nf<7][l][jj] = Wbig[j][o]; j=kc*32+((l>>4)<<3)+jj, o=nf*16+(l&15)
// Wbig[j][o] = (j<600 && o<100 && j/300==o/50) ? wkv_w[100+o][j%300] : 0
__global__ void k_prep(const float* __restrict__ wkv_w, const float* __restrict__ wq_w,
                       const float* __restrict__ wq_b, const float* __restrict__ time_b,
                       const float* __restrict__ wout_w,
                       float* __restrict__ zq, float* __restrict__ wout_t,
                       unsigned short* __restrict__ Bv) {
    int idx = blockIdx.x * 256 + threadIdx.x;
    if (idx < 100) {
        float acc = wq_b[idx];
        for (int j = 0; j < 100; ++j)
            acc += cosf(time_b[j]) * wq_w[idx * 200 + 100 + j];
        zq[idx] = acc;
    } else if (idx < 20100) {
        int r = idx - 100;                      // wout_t[i][o] = wout_w[o][i]
        wout_t[r] = wout_w[(size_t)(r % 100) * 200 + r / 100];
    } else if (idx < 95364) {
        int r2 = idx - 20100;
        int jj = r2 & 7, l = (r2 >> 3) & 63, nf = (r2 >> 9) % 7, kc = r2 / 3584;
        int j = kc * 32 + ((l >> 4) << 3) + jj;
        int o = nf * 16 + (l & 15);
        float v = (j < 600 && o < 100 && (j / 300 == o / 50))
                  ? wkv_w[(size_t)(100 + o) * 300 + (j % 300)] : 0.f;
        Bv[r2] = f2bf(v);
    }
}

// ---------- A2/C2: fold Q-projection into QW map (j<600: X dims; j=600+h: K-bias dot) ----------
__global__ void k_precomp(const float* __restrict__ wq_w, const float* __restrict__ wkv_w,
                          const float* __restrict__ wkv_b, const float* __restrict__ zq,
                          float* __restrict__ A2, float* __restrict__ C2) {
    int idx = blockIdx.x * 256 + threadIdx.x;
    if (idx < 60200) {
        int i = idx / 602, j = idx % 602;
        float acc = 0.f;
        if (j < 600) {
            int h = j / 300, cc = j % 300;
            const float* __restrict__ wq = wq_w + (size_t)(h * 50) * 200 + i;
            const float* __restrict__ wk = wkv_w + (size_t)(h * 50) * 300 + cc;
            #pragma unroll 10
            for (int d = 0; d < 50; ++d)
                acc = fmaf(wq[(size_t)d * 200], wk[(size_t)d * 300], acc);
        } else {
            int h = j - 600;
            const float* __restrict__ wq = wq_w + (size_t)(h * 50) * 200 + i;
            for (int d = 0; d < 50; ++d)
                acc = fmaf(wq[(size_t)d * 200], wkv_b[h * 50 + d], acc);
        }
        A2[idx] = acc;
    } else if (idx < 60802) {
        int j = idx - 60200;
        float acc = 0.f;
        if (j < 600) {
            int h = j / 300, cc = j % 300;
            for (int d = 0; d < 50; ++d)
                acc = fmaf(zq[h * 50 + d], wkv_w[(size_t)(h * 50 + d) * 300 + cc], acc);
        } else {
            int h = j - 600;
            for (int d = 0; d < 50; ++d)
                acc = fmaf(zq[h * 50 + d], wkv_b[h * 50 + d], acc);
        }
        C2[j] = acc;
    }
}

// ---------- Bq pack: A2 -> MFMA B-frag order. Bq[p<2][kc<4][nf<19][l][jj] ----------
// val = A2[k][c], k = kc*32+((l>>4)<<3)+jj (<100), c = p*304+nf*16+(l&15) (<602)
__global__ void k_pack(const float* __restrict__ A2, unsigned short* __restrict__ Bq) {
    int idx = blockIdx.x * 256 + threadIdx.x;
    if (idx >= 77824) return;
    int jj = idx & 7, l = (idx >> 3) & 63, nf = (idx >> 9) % 19, kcp = idx / 9728;
    int kc = kcp & 3, p = kcp >> 2;
    int k = kc * 32 + ((l >> 4) << 3) + jj;
    int c = p * 304 + nf * 16 + (l & 15);
    float v = (k < 100 && c < 602) ? A2[(size_t)k * 602 + c] : 0.f;
    Bq[idx] = f2bf(v);
}

// ---------- CSR offsets via binary search over sorted edge_dst ----------
__global__ void k_offsets(const int* __restrict__ dst, int* __restrict__ off) {
    int n = blockIdx.x * 256 + threadIdx.x;
    if (n > N_DST) return;
    int lo = 0, hi = N_EDGE;
    while (lo < hi) {
        int mid = (lo + hi) >> 1;
        if (dst[mid] < n) lo = mid + 1; else hi = mid;
    }
    off[n] = lo;
}

// ---------- k_qw (MFMA): QW[32768x602] = dst_h[32768x100] @ A2 + C2 ----------
// wave = 16 nodes; K=128 (4 kc); N=608 in 2 passes x 19 frags; acc init = C2.
__global__ __launch_bounds__(256, 1) void k_qw(
        const float* __restrict__ dst_h, const unsigned short* __restrict__ Bq,
        const float* __restrict__ C2, float* __restrict__ QW) {
    __shared__ alignas(16) unsigned short Bs[9728];   // one (p,kc) slab: 19 x 64 x 8
    const int t = threadIdx.x, lane = t & 63;
    const int g = blockIdx.x * 4 + (t >> 6);
    const int col = lane & 15, slice = lane >> 4;
    const int row = g * 16 + col;

    short8b af[4];
    {
        const float* __restrict__ dr = dst_h + (size_t)row * 100;
        #pragma unroll
        for (int kc = 0; kc < 4; ++kc) {
            int k0 = kc * 32 + slice * 8;
            float4 xa = make_float4(0.f, 0.f, 0.f, 0.f), xb = xa;
            if (k0 + 8 <= 100) { xa = *(const float4*)(dr + k0); xb = *(const float4*)(dr + k0 + 4); }
            else if (k0 < 100)  { xa = *(const float4*)(dr + k0); }   // k0 == 96
            short8b a;
            a[0] = (short)f2bf(xa.x); a[1] = (short)f2bf(xa.y);
            a[2] = (short)f2bf(xa.z); a[3] = (short)f2bf(xa.w);
            a[4] = (short)f2bf(xb.x); a[5] = (short)f2bf(xb.y);
            a[6] = (short)f2bf(xb.z); a[7] = (short)f2bf(xb.w);
            af[kc] = a;
        }
    }
    const int re0 = g * 16 + (slice << 2);
    #pragma unroll
    for (int p = 0; p < 2; ++p) {
        f32x4 acc[19];
        #pragma unroll
        for (int nf = 0; nf < 19; ++nf) {
            int c = p * 304 + nf * 16 + col;
            float b = (c < 602) ? C2[c] : 0.f;
            acc[nf] = (f32x4){b, b, b, b};
        }
        #pragma unroll
        for (int kc = 0; kc < 4; ++kc) {
            {   // stage slab (p,kc): 1216 float4
                const float4* __restrict__ ws4 = (const float4*)Bq + (size_t)(p * 4 + kc) * 1216;
                float4* __restrict__ wd = (float4*)Bs;
                #pragma unroll
                for (int i = 0; i < 4; ++i) wd[i * 256 + t] = ws4[i * 256 + t];
                if (t < 192) wd[1024 + t] = ws4[1024 + t];
            }
            __syncthreads();
            #pragma unroll
            for (int nf = 0; nf < 19; ++nf) {
                short8b w = *(const short8b*)(&Bs[(size_t)(nf * 64 + lane) * 8]);
                acc[nf] = __builtin_amdgcn_mfma_f32_16x16x32_bf16(af[kc], w, acc[nf], 0, 0, 0);
            }
            __syncthreads();
        }
        #pragma unroll
        for (int nf = 0; nf < 19; ++nf) {
            int c = p * 304 + nf * 16 + col;
            if (c < 602) {
                #pragma unroll
                for (int r = 0; r < 4; ++r)
                    QW[(size_t)(re0 + r) * 608 + c] = acc[nf][r];
            }
        }
    }
}

// ---------- k_node: flash streaming pass (round-20 proven), Xagg -> HBM ----------
__global__ __launch_bounds__(256) void k_node(
        const float* __restrict__ src_h, const float* __restrict__ efeat,
        const float* __restrict__ td,
        const float* __restrict__ time_w, const float* __restrict__ time_b,
        const float* __restrict__ QW, const int* __restrict__ off,
        float* __restrict__ Xagg) {
    const int lane = threadIdx.x & 63;
    const int n = blockIdx.x * 4 + (threadIdx.x >> 6);
    const int r0 = off[n], cnt = off[n + 1] - r0;
    float* __restrict__ xo = Xagg + (size_t)n * 600;
    if (cnt <= 0) {
        #pragma unroll
        for (int s = 0; s < 5; ++s) {
            int cc = s * 64 + lane;
            if (cc < 300) { xo[cc] = 0.f; xo[300 + cc] = 0.f; }
        }
        return;
    }
    float qw0[5], qw1[5];
    #pragma unroll
    for (int s = 0; s < 5; ++s) {
        int cc = s * 64 + lane;
        qw0[s] = (cc < 300) ? QW[(size_t)n * 608 + cc]       : 0.f;
        qw1[s] = (cc < 300) ? QW[(size_t)n * 608 + 300 + cc] : 0.f;
    }
    const float B0 = QW[(size_t)n * 608 + 600];
    const float B1 = QW[(size_t)n * 608 + 601];
    float tw3 = 0.f, tb3 = 0.f, tw4 = 0.f, tb4 = 0.f;
    if (lane >= 8) { tw3 = time_w[lane - 8]; tb3 = time_b[lane - 8]; }
    if (lane < 44) { tw4 = time_w[56 + lane]; tb4 = time_b[56 + lane]; }

    auto LOADX = [&](float* x, int r) {
        const float* __restrict__ sr = src_h + (size_t)r * 100;
        const float* __restrict__ er = efeat + (size_t)r * 100;
        const float tdv = td[r];
        x[0] = sr[lane];
        x[1] = (lane < 36) ? sr[64 + lane] : er[lane - 36];
        x[2] = er[28 + lane];
        x[3] = (lane < 8) ? er[92 + lane] : __cosf(fmaf(tdv, tw3, tb3));
        x[4] = (lane < 44) ? __cosf(fmaf(tdv, tw4, tb4)) : 0.f;
    };

    float m0 = -1e30f, m1 = -1e30f, sum0 = 0.f, sum1 = 0.f;
    float a0[5] = {0.f, 0.f, 0.f, 0.f, 0.f}, a1[5] = {0.f, 0.f, 0.f, 0.f, 0.f};

    auto UPDATE = [&](float l0, float l1, const float* x) {
        l0 = l0 > 0.f ? l0 : 0.2f * l0;
        l1 = l1 > 0.f ? l1 : 0.2f * l1;
        if (l0 <= m0 && l1 <= m1) {
            float w0 = __expf(l0 - m0), w1 = __expf(l1 - m1);
            sum0 += w0; sum1 += w1;
            #pragma unroll
            for (int s = 0; s < 5; ++s) {
                a0[s] = fmaf(w0, x[s], a0[s]);
                a1[s] = fmaf(w1, x[s], a1[s]);
            }
        } else {
            float m0n = fmaxf(m0, l0), m1n = fmaxf(m1, l1);
            float r0f = __expf(m0 - m0n), r1f = __expf(m1 - m1n);
            float w0 = __expf(l0 - m0n),  w1 = __expf(l1 - m1n);
            sum0 = fmaf(sum0, r0f, w0);
            sum1 = fmaf(sum1, r1f, w1);
            #pragma unroll
            for (int s = 0; s < 5; ++s) {
                a0[s] = fmaf(a0[s], r0f, w0 * x[s]);
                a1[s] = fmaf(a1[s], r1f, w1 * x[s]);
            }
            m0 = m0n; m1 = m1n;
        }
    };

    float xA[5], xB[5], xC[5], xD[5];
    int i = 0;
    if (cnt >= 2) {
        LOADX(xA, r0); LOADX(xB, r0 + 1);
        for (; i + 2 <= cnt; i += 2) {
            float pA0 = 0.f, pA1 = 0.f, pB0 = 0.f, pB1 = 0.f;
            #pragma unroll
            for (int s = 0; s < 5; ++s) {
                pA0 = fmaf(xA[s], qw0[s], pA0); pA1 = fmaf(xA[s], qw1[s], pA1);
                pB0 = fmaf(xB[s], qw0[s], pB0); pB1 = fmaf(xB[s], qw1[s], pB1);
            }
            #pragma unroll
            for (int sh = 1; sh < 64; sh <<= 1) {
                pA0 += __shfl_xor(pA0, sh); pA1 += __shfl_xor(pA1, sh);
                pB0 += __shfl_xor(pB0, sh); pB1 += __shfl_xor(pB1, sh);
            }
            if (i + 2 < cnt) LOADX(xC, r0 + i + 2);
            if (i + 3 < cnt) LOADX(xD, r0 + i + 3);
            UPDATE(pA0 + B0, pA1 + B1, xA);
            UPDATE(pB0 + B0, pB1 + B1, xB);
            #pragma unroll
            for (int s = 0; s < 5; ++s) { xA[s] = xC[s]; xB[s] = xD[s]; }
        }
    } else {
        LOADX(xA, r0);
    }
    if (i < cnt) {
        float p0 = 0.f, p1 = 0.f;
        #pragma unroll
        for (int s = 0; s < 5; ++s) {
            p0 = fmaf(xA[s], qw0[s], p0);
            p1 = fmaf(xA[s], qw1[s], p1);
        }
        #pragma unroll
        for (int sh = 1; sh < 64; sh <<= 1) {
            p0 += __shfl_xor(p0, sh); p1 += __shfl_xor(p1, sh);
        }
        UPDATE(p0 + B0, p1 + B1, xA);
    }
    const float inv0 = 1.f / sum0, inv1 = 1.f / sum1;
    #pragma unroll
    for (int s = 0; s < 5; ++s) {
        int cc = s * 64 + lane;
        if (cc < 300) {
            xo[cc]       = a0[s] * inv0;
            xo[300 + cc] = a1[s] * inv1;
        }
    }
}

// ---------- k_aggv (MFMA): agg[32768x100] = Xagg[32768x600] @ Wbig + has*b_v ----------
// wave = 16 nodes; K=672 (21 kc, >=600 zero); N=112 (7 frags); 3-kc LDS slabs.
__global__ __launch_bounds__(256, 1) void k_aggv(
        const float* __restrict__ Xagg, const unsigned short* __restrict__ Bv,
        const float* __restrict__ wkv_b, const int* __restrict__ off,
        float* __restrict__ agg) {
    __shared__ alignas(16) unsigned short Bs[10752];  // 3-kc slab: 3 x 7 x 64 x 8
    const int t = threadIdx.x, lane = t & 63;
    const int g = blockIdx.x * 4 + (t >> 6);
    const int col = lane & 15, slice = lane >> 4;
    const int row = g * 16 + col;

    short8b af[21];
    {
        const float* __restrict__ xr = Xagg + (size_t)row * 600;
        #pragma unroll
        for (int kc = 0; kc < 21; ++kc) {
            int j0 = kc * 32 + slice * 8;
            float4 xa = make_float4(0.f, 0.f, 0.f, 0.f), xb = xa;
            if (j0 + 8 <= 600) { xa = *(const float4*)(xr + j0); xb = *(const float4*)(xr + j0 + 4); }
            short8b a;
            a[0] = (short)f2bf(xa.x); a[1] = (short)f2bf(xa.y);
            a[2] = (short)f2bf(xa.z); a[3] = (short)f2bf(xa.w);
            a[4] = (short)f2bf(xb.x); a[5] = (short)f2bf(xb.y);
            a[6] = (short)f2bf(xb.z); a[7] = (short)f2bf(xb.w);
            af[kc] = a;
        }
    }
    f32x4 acc[7];
    #pragma unroll
    for (int nf = 0; nf < 7; ++nf) acc[nf] = (f32x4){0.f, 0.f, 0.f, 0.f};

    #pragma unroll
    for (int slab = 0; slab < 7; ++slab) {
        {   // stage 3-kc slab: 1344 float4 = 5*256 + 64
            const float4* __restrict__ ws4 = (const float4*)Bv + (size_t)slab * 1344;
            float4* __restrict__ wd = (float4*)Bs;
            #pragma unroll
            for (int i = 0; i < 5; ++i) wd[i * 256 + t] = ws4[i * 256 + t];
            if (t < 64) wd[1280 + t] = ws4[1280 + t];
        }
        __syncthreads();
        #pragma unroll
        for (int kl = 0; kl < 3; ++kl) {
            const int kc = slab * 3 + kl;
            #pragma unroll
            for (int nf = 0; nf < 7; ++nf) {
                short8b w = *(const short8b*)(&Bs[(size_t)((kl * 7 + nf) * 64 + lane) * 8]);
                acc[nf] = __builtin_amdgcn_mfma_f32_16x16x32_bf16(af[kc], w, acc[nf], 0, 0, 0);
            }
        }
        __syncthreads();
    }
    const int re0 = g * 16 + (slice << 2);
    #pragma unroll
    for (int nf = 0; nf < 7; ++nf) {
        int o = nf * 16 + col;
        if (o < 100) {
            float bv = wkv_b[100 + o];
            #pragma unroll
            for (int r = 0; r < 4; ++r) {
                int node = re0 + r;
                bool has = off[node + 1] > off[node];
                agg[(size_t)node * 100 + o] = acc[nf][r] + (has ? bv : 0.f);
            }
        }
    }
}

// ---------- out proj + relu + layernorm: 8 nodes/block, coalesced wout_t ----------
__global__ __launch_bounds__(128) void k_out(const float* __restrict__ agg,
                                             const float* __restrict__ dst_h,
                                             const float* __restrict__ wout_t,
                                             const float* __restrict__ wout_b,
                                             const float* __restrict__ ln_g,
                                             const float* __restrict__ ln_b,
                                             float* __restrict__ out) {
    __shared__ float Fs[8][200];
    __shared__ float red[8][128];
    const int n0 = blockIdx.x * 8, t = threadIdx.x;
    for (int idx = t; idx < 1600; idx += 128) {
        int n = idx / 200, i = idx % 200;
        Fs[n][i] = (i < 100) ? agg[(size_t)(n0 + n) * 100 + i]
                             : dst_h[(size_t)(n0 + n) * 100 + (i - 100)];
    }
    __syncthreads();
    float v[8] = {0.f, 0.f, 0.f, 0.f, 0.f, 0.f, 0.f, 0.f};
    if (t < 100) {
        float b = wout_b[t];
        #pragma unroll
        for (int n = 0; n < 8; ++n) v[n] = b;
        for (int i = 0; i < 200; ++i) {
            float w = wout_t[i * 100 + t];
            #pragma unroll
            for (int n = 0; n < 8; ++n) v[n] = fmaf(Fs[n][i], w, v[n]);
        }
        #pragma unroll
        for (int n = 0; n < 8; ++n) v[n] = fmaxf(v[n], 0.f);
    }
    #pragma unroll
    for (int n = 0; n < 8; ++n) red[n][t] = (t < 100) ? v[n] : 0.f;
    __syncthreads();
    for (int s = 64; s > 0; s >>= 1) {
        if (t < s) {
            #pragma unroll
            for (int n = 0; n < 8; ++n) red[n][t] += red[n][t + s];
        }
        __syncthreads();
    }
    float mu[8];
    #pragma unroll
    for (int n = 0; n < 8; ++n) mu[n] = red[n][0] * 0.01f;
    __syncthreads();
    #pragma unroll
    for (int n = 0; n < 8; ++n) {
        float dv = (t < 100) ? (v[n] - mu[n]) : 0.f;
        red[n][t] = dv * dv;
    }
    __syncthreads();
    for (int s = 64; s > 0; s >>= 1) {
        if (t < s) {
            #pragma unroll
            for (int n = 0; n < 8; ++n) red[n][t] += red[n][t + s];
        }
        __syncthreads();
    }
    if (t < 100) {
        #pragma unroll
        for (int n = 0; n < 8; ++n) {
            float var = red[n][0] * 0.01f;
            out[(size_t)(n0 + n) * 100 + t] =
                (v[n] - mu[n]) * rsqrtf(var + LN_EPS) * ln_g[t] + ln_b[t];
        }
    }
}

extern "C" void kernel_launch(void* const* d_in, const int* in_sizes, int n_in,
                              void* d_out, int out_size, void* d_ws, size_t ws_size,
                              hipStream_t stream) {
    const float* dst_h   = (const float*)d_in[0];
    const float* src_h   = (const float*)d_in[1];
    const float* efeat   = (const float*)d_in[2];
    const float* td      = (const float*)d_in[3];
    const int*   edst    = (const int*)  d_in[4];
    const float* time_w  = (const float*)d_in[5];
    const float* time_b  = (const float*)d_in[6];
    const float* wq_w    = (const float*)d_in[7];
    const float* wq_b    = (const float*)d_in[8];
    const float* wkv_w   = (const float*)d_in[9];
    const float* wkv_b   = (const float*)d_in[10];
    const float* wout_w  = (const float*)d_in[11];
    const float* wout_b  = (const float*)d_in[12];
    const float* ln_g    = (const float*)d_in[13];
    const float* ln_b    = (const float*)d_in[14];
    float* out = (float*)d_out;

    char* ws = (char*)d_ws;
    size_t off = 0;
    auto carve = [&](size_t bytes) { char* p = ws + off; off = (off + bytes + 255) & ~(size_t)255; return p; };
    float*          QW    = (float*)carve((size_t)N_DST * 608 * 4);
    float*          Xagg  = (float*)carve((size_t)N_DST * 600 * 4);
    float*          agg   = (float*)carve((size_t)N_DST * 100 * 4);
    float*          A2    = (float*)carve(60200 * 4);
    float*          C2    = (float*)carve(602 * 4);
    unsigned short* Bq    = (unsigned short*)carve(77824 * 2);
    unsigned short* Bv    = (unsigned short*)carve(75264 * 2);
    float*          woutT = (float*)carve(20000 * 4);
    float*          zq    = (float*)carve(100 * 4);
    int*            offs  = (int*)carve((size_t)(N_DST + 1) * 4);

    k_prep<<<(95364 + 255) / 256, 256, 0, stream>>>(wkv_w, wq_w, wq_b, time_b, wout_w,
                                                    zq, woutT, Bv);
    k_precomp<<<(60802 + 255) / 256, 256, 0, stream>>>(wq_w, wkv_w, wkv_b, zq, A2, C2);
    k_pack<<<(77824 + 255) / 256, 256, 0, stream>>>(A2, Bq);
    k_offsets<<<(N_DST + 1 + 255) / 256, 256, 0, stream>>>(edst, offs);
    k_qw<<<N_DST / 64, 256, 0, stream>>>(dst_h, Bq, C2, QW);
    k_node<<<N_DST / 4, 256, 0, stream>>>(src_h, efeat, td, time_w, time_b,
                                          QW, offs, Xagg);
    k_aggv<<<N_DST / 64, 256, 0, stream>>>(Xagg, Bv, wkv_b, offs, agg);
    k_out<<<N_DST / 8, 128, 0, stream>>>(agg, dst_h, woutT, wout_b, ln_g, ln_b, out);
}